// Round 12
// baseline (843.762 us; speedup 1.0000x reference)
//
#include <hip/hip_runtime.h>
#include <math.h>

#define B_ 8
#define N_ 16384
#define G_ 128      // NUM_GROUPS
#define GS_ 32      // GROUP_SIZE
#define UK_ 128     // UPSCALE_K
#define FPS_T 1024
#define FPS_W 16    // waves per FPS block
#define FPS_BLK 4   // blocks (CUs) per batch
#define NSLOT (FPS_BLK * FPS_W)  // 64 (block,wave) slots per (b,k)
#define SLICE (N_ / FPS_BLK)     // 4096 points per block
#define PPT (SLICE / FPS_T)      // 4 points per thread
#define BQ_T 512
#define BQ_W 8      // waves per group block

// Exact-rounding distance^2, matching numpy: ((dx*dx + dy*dy) + dz*dz), no FMA.
__device__ __forceinline__ float dist2(float x, float y, float z,
                                       float cx, float cy, float cz) {
    float dx = __fsub_rn(x, cx);
    float dy = __fsub_rn(y, cy);
    float dz = __fsub_rn(z, cz);
    return __fadd_rn(__fadd_rn(__fmul_rn(dx, dx), __fmul_rn(dy, dy)),
                     __fmul_rn(dz, dz));
}

// Wave64 max-reduce on the VALU pipe via DPP (no DS traffic); identity 0.
// (Our keys are always nonzero: monotone code of any non-NaN float != 0.)
__device__ __forceinline__ unsigned wave_umax_bcast(unsigned v) {
    unsigned t;
    t = (unsigned)__builtin_amdgcn_update_dpp(0, (int)v, 0x111, 0xf, 0xf, false); v = v > t ? v : t;
    t = (unsigned)__builtin_amdgcn_update_dpp(0, (int)v, 0x112, 0xf, 0xf, false); v = v > t ? v : t;
    t = (unsigned)__builtin_amdgcn_update_dpp(0, (int)v, 0x114, 0xf, 0xf, false); v = v > t ? v : t;
    t = (unsigned)__builtin_amdgcn_update_dpp(0, (int)v, 0x118, 0xf, 0xf, false); v = v > t ? v : t;
    t = (unsigned)__builtin_amdgcn_update_dpp(0, (int)v, 0x142, 0xa, 0xf, false); v = v > t ? v : t;
    t = (unsigned)__builtin_amdgcn_update_dpp(0, (int)v, 0x143, 0xc, 0xf, false); v = v > t ? v : t;
    return (unsigned)__builtin_amdgcn_readlane((int)v, 63);
}
__device__ __forceinline__ unsigned wave_umin_bcast(unsigned v) {
    unsigned t;
    t = (unsigned)__builtin_amdgcn_update_dpp(-1, (int)v, 0x111, 0xf, 0xf, false); v = v < t ? v : t;
    t = (unsigned)__builtin_amdgcn_update_dpp(-1, (int)v, 0x112, 0xf, 0xf, false); v = v < t ? v : t;
    t = (unsigned)__builtin_amdgcn_update_dpp(-1, (int)v, 0x114, 0xf, 0xf, false); v = v < t ? v : t;
    t = (unsigned)__builtin_amdgcn_update_dpp(-1, (int)v, 0x118, 0xf, 0xf, false); v = v < t ? v : t;
    t = (unsigned)__builtin_amdgcn_update_dpp(-1, (int)v, 0x142, 0xa, 0xf, false); v = v < t ? v : t;
    t = (unsigned)__builtin_amdgcn_update_dpp(-1, (int)v, 0x143, 0xc, 0xf, false); v = v < t ? v : t;
    return (unsigned)__builtin_amdgcn_readlane((int)v, 63);
}

// ---------------------------------------------------------------------------
// Kernel 0: zero the cross-block slots + gl (ws is poisoned 0xAA).
// 64 blocks x 1024 threads, one u64 each.
// ---------------------------------------------------------------------------
__global__ void init_kernel(unsigned long long* __restrict__ slots,
                            int* __restrict__ gl) {
    int i = blockIdx.x * 1024 + threadIdx.x;
    slots[i] = 0ull;
    if (i < B_) gl[i] = 0;
}

// ---------------------------------------------------------------------------
// Kernel 1: FPS, 4 blocks per batch, ZERO in-loop barriers.
//
// r11 post-mortem: the bulk-synchronous skeleton itself cost ~2000 cyc/step
// (2x syncthreads, 8 dependent u64 shfls in wave0's merge, LDS broadcast).
// This round: flat 64-way sync. Each (block,wave) DPP-reduces its partial
// and lane0 relax-stores it to slot[slice*16+wv] (fresh 64-slot array per
// step). Every wave then independently polls all 64 slots (lane i owns
// slot i, one dwordx2/lane) and merges via two-phase DPP (max hi32 dist
// key, then max lo32=~idx among hi-ties = min index) -- bit-identical
// winner. Intra-block waves share NOTHING inside the loop (s_xy4
// read-only after staging; s_cen written by wave0-lane0, read by wave0
// only => in-wave ordered), so no __syncthreads is needed.
// ---------------------------------------------------------------------------
__global__ __launch_bounds__(FPS_T, 4) void fps_cnms_kernel(
    const float4* __restrict__ pts, const int* __restrict__ lengths,
    float* __restrict__ centers_out, int* __restrict__ keep_out,
    unsigned long long* __restrict__ slots) {
    const int b = blockIdx.x & 7;        // batch
    const int slice = blockIdx.x >> 3;   // 0..3
    const int t = threadIdx.x;
    const int lane = t & 63;
    const int wv = t >> 6;
    const int len = lengths[b];
    const float4* p = pts + (size_t)b * N_;
    const int base = slice * SLICE;

    __shared__ float4 s_xy4[SLICE / 2];                   // 32 KB: (xA,yA,xB,yB)
    __shared__ float s_cen[G_][3];                        // CNMS (slice-0, wave-0 only)

    // Stage xy pairs -> LDS; z + running min-dist in registers.
    float zs[PPT], mind[PPT];
#pragma unroll
    for (int i2 = 0; i2 < PPT / 2; i2++) {
        int nA = base + (2 * i2) * FPS_T + t;
        int nB = base + (2 * i2 + 1) * FPS_T + t;
        float4 qA = p[nA];
        float4 qB = p[nB];
        s_xy4[i2 * FPS_T + t] = make_float4(qA.x, qA.y, qB.x, qB.y);
        zs[2 * i2]     = qA.z;
        zs[2 * i2 + 1] = qB.z;
        mind[2 * i2]     = (nA < len) ? INFINITY : -INFINITY;
        mind[2 * i2 + 1] = (nB < len) ? INFINITY : -INFINITY;
    }
    __syncthreads();   // the ONLY barrier: s_xy4 becomes read-only after this

    int n = 0;   // winner index (identical in every wave of batch b)
    for (int k = 0; k < G_; k++) {
        float4 c = p[n];   // wave-uniform broadcast load (L2 hit)
        float cx = c.x, cy = c.y, cz = c.z;
        if (slice == 0 && t == 0) {
            centers_out[(b * G_ + k) * 3 + 0] = cx;
            centers_out[(b * G_ + k) * 3 + 1] = cy;
            centers_out[(b * G_ + k) * 3 + 2] = cz;
            s_cen[k][0] = cx; s_cen[k][1] = cy; s_cen[k][2] = cz;
        }
        if (k == G_ - 1) break;   // last argmax is discarded by the reference

        // Local update + argmax (ascending n order => strict > keeps smallest n).
        float bv = -INFINITY;
        int bn = 0x7fffffff;
#pragma unroll
        for (int i2 = 0; i2 < PPT / 2; i2++) {
            float4 xy = s_xy4[i2 * FPS_T + t];            // ds_read_b128, 2 points
            float dA = dist2(xy.x, xy.y, zs[2 * i2],     cx, cy, cz);
            float dB = dist2(xy.z, xy.w, zs[2 * i2 + 1], cx, cy, cz);
            float mA = fminf(mind[2 * i2], dA);
            float mB = fminf(mind[2 * i2 + 1], dB);
            mind[2 * i2] = mA;
            mind[2 * i2 + 1] = mB;
            if (mA > bv) { bv = mA; bn = base + (2 * i2) * FPS_T + t; }
            if (mB > bv) { bv = mB; bn = base + (2 * i2 + 1) * FPS_T + t; }
        }
        // Monotone u32 key of bv (any non-NaN float -> nonzero code).
        unsigned u = __float_as_uint(bv);
        u = (u & 0x80000000u) ? ~u : (u | 0x80000000u);

        // Wave argmax (VALU pipe): max value, then min index among ties.
        unsigned wmax = wave_umax_bcast(u);
        unsigned ik = (u == wmax) ? (unsigned)bn : 0xffffffffu;
        unsigned wbn = wave_umin_bcast(ik);
        unsigned long long kk =
            ((unsigned long long)wmax << 32) | (unsigned)(~wbn);

        // Flat 64-way exchange: store own partial, poll all 64, DPP merge.
        unsigned long long* slot = slots + ((size_t)(b * G_ + k)) * NSLOT;
        if (lane == 0)
            __hip_atomic_store(&slot[slice * FPS_W + wv], kk, __ATOMIC_RELAXED,
                               __HIP_MEMORY_SCOPE_AGENT);
        unsigned long long v;
        do {
            v = __hip_atomic_load(&slot[lane], __ATOMIC_RELAXED,
                                  __HIP_MEMORY_SCOPE_AGENT);
        } while (__ballot(v == 0ull) != 0ull);

        unsigned hi = (unsigned)(v >> 32);
        unsigned mh = wave_umax_bcast(hi);
        unsigned lo = (hi == mh) ? (unsigned)(v & 0xffffffffull) : 0u;
        unsigned ml = wave_umax_bcast(lo);   // max ~idx among ties = min idx
        n = (int)(~ml);
    }

    if (t == FPS_T - 1) gl_global_store: ;
    if (slice == FPS_BLK - 1 && t == FPS_T - 1) {
        // nothing: gl zeroed by init_kernel
    }

    // ---- fused CNMS on wave 0 of the slice-0 block ----
    if (slice == 0 && t < 64) {
        const float THR = (float)((2.0 * 0.1 * (1.0 - 0.7)) * (2.0 * 0.1 * (1.0 - 0.7)));
        float ax = s_cen[t][0],      ay = s_cen[t][1],      az = s_cen[t][2];
        float ex = s_cen[t + 64][0], ey = s_cen[t + 64][1], ez = s_cen[t + 64][2];
        bool k0 = false, k1 = false;
        for (int j = 0; j < G_; j++) {
            float jx = s_cen[j][0], jy = s_cen[j][1], jz = s_cen[j][2];
            bool c0 = k0 && (dist2(ax, ay, az, jx, jy, jz) < THR);
            bool c1 = k1 && (dist2(ex, ey, ez, jx, jy, jz) < THR);
            bool conflict = __any(c0 || c1);
            if (j == t)      k0 = !conflict;
            if (j == t + 64) k1 = !conflict;
        }
        keep_out[b * G_ + t]      = k0 ? 1 : 0;
        keep_out[b * G_ + t + 64] = k1 ? 1 : 0;
    }
}

// ---------------------------------------------------------------------------
// Kernel 2: per-(b,g) ball query (first 128 by index) + top-32 by energy +
// gather/normalize. One 512-thread block per group.
// ---------------------------------------------------------------------------
__global__ __launch_bounds__(BQ_T) void group_kernel(
    const float4* __restrict__ pts, const int* __restrict__ lengths,
    const float* __restrict__ centers, const int* __restrict__ keep,
    float* __restrict__ groups_out, int* __restrict__ gl) {
    const int bid = blockIdx.x;          // b*128 + g
    const int b = bid >> 7;
    const int t = threadIdx.x;
    const int lane = t & 63;
    const int wv = t >> 6;

    const float cx = centers[bid * 3 + 0];
    const float cy = centers[bid * 3 + 1];
    const float cz = centers[bid * 3 + 2];
    float4* out4 = (float4*)(groups_out + (size_t)bid * GS_ * 4);

    if (!keep[bid]) {
        if (t < GS_) {
            float4 o;
            o.x = __fdiv_rn(__fsub_rn(0.f, cx), 0.1f);
            o.y = __fdiv_rn(__fsub_rn(0.f, cy), 0.1f);
            o.z = __fdiv_rn(__fsub_rn(0.f, cz), 0.1f);
            o.w = 0.f;
            out4[t] = o;
        }
        return;
    }

    __shared__ int   s_widx[BQ_W][UK_];
    __shared__ float s_wen[BQ_W][UK_];
    __shared__ int   s_wcnt[BQ_W];
    __shared__ int   s_list[UK_];
    __shared__ float s_en[UK_];
    __shared__ int   s_ord[GS_];

    const int len = lengths[b];
    const float R2 = (float)(0.1 * 0.1);
    const float4* p = pts + (size_t)b * N_;

    // Per-wave ordered stream compaction over its contiguous eighth.
    {
        const int base0 = wv * (N_ / BQ_W);
        int cnt = 0;
        for (int it = 0; it < (N_ / BQ_W) / 64; it++) {
            int n = base0 + it * 64 + lane;
            float4 q = p[n];
            float d2 = dist2(q.x, q.y, q.z, cx, cy, cz);
            bool pred = (n < len) && (d2 <= R2);
            unsigned long long m = __ballot(pred);
            int prefix = __popcll(m & ((1ull << lane) - 1ull));
            int slot = cnt + prefix;
            if (pred && slot < UK_) { s_widx[wv][slot] = n; s_wen[wv][slot] = q.w; }
            cnt += __popcll(m);
        }
        if (lane == 0) s_wcnt[wv] = (cnt < UK_) ? cnt : UK_;
    }
    __syncthreads();

    int M = 0;
#pragma unroll
    for (int w = 0; w < BQ_W; w++) M += s_wcnt[w];
    if (M > UK_) M = UK_;

    // Ordered merge into unified first-M list.
    if (t < UK_ && t < M) {
        int j = t, w = 0;
        while (w < BQ_W - 1 && j >= s_wcnt[w]) { j -= s_wcnt[w]; w++; }
        s_list[t] = s_widx[w][j];
        s_en[t]   = s_wen[w][j];
    }
    __syncthreads();

    // top-32 by energy, tie -> smaller list position (matches lax.top_k)
    if (wv == 0) {
        float v0 = (lane < M) ? s_en[lane] : -INFINITY;
        float v1 = (lane + 64 < M) ? s_en[lane + 64] : -INFINITY;
        for (int k = 0; k < GS_; k++) {
            float bv; int bs;
            if (v0 >= v1) { bv = v0; bs = lane; }
            else          { bv = v1; bs = lane + 64; }
#pragma unroll
            for (int off = 32; off; off >>= 1) {
                float ov = __shfl_xor(bv, off);
                int   os = __shfl_xor(bs, off);
                bool tk = (ov > bv) || (ov == bv && os < bs);
                bv = tk ? ov : bv; bs = tk ? os : bs;
            }
            if (lane == 0) s_ord[k] = (bv == -INFINITY) ? -1 : bs;
            if (bs == lane)           v0 = -INFINITY;
            else if (bs == lane + 64) v1 = -INFINITY;
        }
    }
    __syncthreads();

    if (t < GS_) {
        int o0 = s_ord[0];
        int first = (o0 >= 0) ? s_list[o0] : -1;
        int ok = s_ord[t];
        int ti = (ok >= 0) ? s_list[ok] : -1;
        int f = (ti == -1) ? first : ti;
        float px = 0.f, py = 0.f, pz = 0.f, pw = 0.f;
        if (f >= 0) { float4 q = p[f]; px = q.x; py = q.y; pz = q.z; pw = q.w; }
        float4 o;
        o.x = __fdiv_rn(__fsub_rn(px, cx), 0.1f);
        o.y = __fdiv_rn(__fsub_rn(py, cy), 0.1f);
        o.z = __fdiv_rn(__fsub_rn(pz, cz), 0.1f);
        o.w = __fdiv_rn(pw, 0.1f);
        out4[t] = o;
    }
    if (t == 0 && M >= GS_) atomicAdd(&gl[b], 1);
}

// ---------------------------------------------------------------------------
// Kernel 3: embedding mask
// ---------------------------------------------------------------------------
__global__ void mask_kernel(const int* __restrict__ gl, float* __restrict__ mask_out) {
    int t = threadIdx.x;                 // 1024 threads
    int b = t >> 7, g = t & 127;
    mask_out[t] = (g < gl[b]) ? 1.0f : 0.0f;
}

extern "C" void kernel_launch(void* const* d_in, const int* in_sizes, int n_in,
                              void* d_out, int out_size, void* d_ws, size_t ws_size,
                              hipStream_t stream) {
    const float4* pts = (const float4*)d_in[0];
    const int* lengths = (const int*)d_in[1];
    float* out = (float*)d_out;
    float* groups = out;                               // B*G*GS*4 = 131072
    float* centers = out + (size_t)B_ * G_ * GS_ * 4;  // +3072
    float* mask = centers + (size_t)B_ * G_ * 3;       // +1024
    unsigned long long* slots = (unsigned long long*)d_ws;  // B*G*NSLOT u64 = 512 KB
    int* keep = (int*)(slots + (size_t)B_ * G_ * NSLOT);    // B*G ints
    int* gl = keep + B_ * G_;                          // B ints

    hipLaunchKernelGGL(init_kernel, dim3((B_ * G_ * NSLOT) / 1024), dim3(1024),
                       0, stream, slots, gl);
    hipLaunchKernelGGL(fps_cnms_kernel, dim3(B_ * FPS_BLK), dim3(FPS_T), 0, stream,
                       pts, lengths, centers, keep, slots);
    hipLaunchKernelGGL(group_kernel, dim3(B_ * G_), dim3(BQ_T), 0, stream,
                       pts, lengths, centers, keep, groups, gl);
    hipLaunchKernelGGL(mask_kernel, dim3(1), dim3(B_ * G_), 0, stream, gl, mask);
}

// Round 13
// 387.286 us; speedup vs baseline: 2.1787x; 2.1787x over previous
//
#include <hip/hip_runtime.h>
#include <math.h>

#define B_ 8
#define N_ 16384
#define G_ 128      // NUM_GROUPS
#define GS_ 32      // GROUP_SIZE
#define UK_ 128     // UPSCALE_K
#define FPS_T 1024
#define FPS_W 16    // waves per FPS block
#define FPS_BLK 4   // blocks (CUs) per batch
#define NSLOT (FPS_BLK * FPS_W)  // 64 (block,wave) slots per (b,k)
#define SLICE (N_ / FPS_BLK)     // 4096 points per block
#define PPT (SLICE / FPS_T)      // 4 points per thread
#define BQ_T 512
#define BQ_W 8      // waves per group block

// Exact-rounding distance^2, matching numpy: ((dx*dx + dy*dy) + dz*dz), no FMA.
__device__ __forceinline__ float dist2(float x, float y, float z,
                                       float cx, float cy, float cz) {
    float dx = __fsub_rn(x, cx);
    float dy = __fsub_rn(y, cy);
    float dz = __fsub_rn(z, cz);
    return __fadd_rn(__fadd_rn(__fmul_rn(dx, dx), __fmul_rn(dy, dy)),
                     __fmul_rn(dz, dz));
}

// Wave64 max-reduce on the VALU pipe via DPP (no DS traffic); identity 0.
__device__ __forceinline__ unsigned wave_umax_bcast(unsigned v) {
    unsigned t;
    t = (unsigned)__builtin_amdgcn_update_dpp(0, (int)v, 0x111, 0xf, 0xf, false); v = v > t ? v : t;
    t = (unsigned)__builtin_amdgcn_update_dpp(0, (int)v, 0x112, 0xf, 0xf, false); v = v > t ? v : t;
    t = (unsigned)__builtin_amdgcn_update_dpp(0, (int)v, 0x114, 0xf, 0xf, false); v = v > t ? v : t;
    t = (unsigned)__builtin_amdgcn_update_dpp(0, (int)v, 0x118, 0xf, 0xf, false); v = v > t ? v : t;
    t = (unsigned)__builtin_amdgcn_update_dpp(0, (int)v, 0x142, 0xa, 0xf, false); v = v > t ? v : t;
    t = (unsigned)__builtin_amdgcn_update_dpp(0, (int)v, 0x143, 0xc, 0xf, false); v = v > t ? v : t;
    return (unsigned)__builtin_amdgcn_readlane((int)v, 63);
}
__device__ __forceinline__ unsigned wave_umin_bcast(unsigned v) {
    unsigned t;
    t = (unsigned)__builtin_amdgcn_update_dpp(-1, (int)v, 0x111, 0xf, 0xf, false); v = v < t ? v : t;
    t = (unsigned)__builtin_amdgcn_update_dpp(-1, (int)v, 0x112, 0xf, 0xf, false); v = v < t ? v : t;
    t = (unsigned)__builtin_amdgcn_update_dpp(-1, (int)v, 0x114, 0xf, 0xf, false); v = v < t ? v : t;
    t = (unsigned)__builtin_amdgcn_update_dpp(-1, (int)v, 0x118, 0xf, 0xf, false); v = v < t ? v : t;
    t = (unsigned)__builtin_amdgcn_update_dpp(-1, (int)v, 0x142, 0xa, 0xf, false); v = v < t ? v : t;
    t = (unsigned)__builtin_amdgcn_update_dpp(-1, (int)v, 0x143, 0xc, 0xf, false); v = v < t ? v : t;
    return (unsigned)__builtin_amdgcn_readlane((int)v, 63);
}

// ---------------------------------------------------------------------------
// Kernel 0: zero the cross-block slots + gl (ws is poisoned 0xAA).
// ---------------------------------------------------------------------------
__global__ void init_kernel(unsigned long long* __restrict__ slots,
                            int* __restrict__ gl) {
    int i = blockIdx.x * 1024 + threadIdx.x;
    slots[i] = 0ull;
    if (i < B_) gl[i] = 0;
}

// ---------------------------------------------------------------------------
// Kernel 1: FPS, 4 blocks per batch, ZERO in-loop barriers.
//
// r12 lesson: polling waves must be FEW (512 pollers -> traffic escaped to
// HBM, FETCH 5.3MB, 772us). This round: all 16 waves relax-store their DPP
// partial to a fresh 64-slot array per step (no LDS partial stage, no
// barrier); ONLY wave 0 of each block polls the 64 slots (4 pollers/batch,
// r11's safe count) and merges via two-phase DPP; result published as a
// stamped b32 in LDS ((k+1)<<14|n); other waves spin on the stamp
// (same-address LDS broadcast). Stamp cannot skip ahead: wave0 can't
// finish step k+1 until every spinning wave stored its k+1 partial.
// ---------------------------------------------------------------------------
__global__ __launch_bounds__(FPS_T, 4) void fps_cnms_kernel(
    const float4* __restrict__ pts, const int* __restrict__ lengths,
    float* __restrict__ centers_out, int* __restrict__ keep_out,
    unsigned long long* __restrict__ slots) {
    const int b = blockIdx.x & 7;        // batch
    const int slice = blockIdx.x >> 3;   // 0..3
    const int t = threadIdx.x;
    const int lane = t & 63;
    const int wv = t >> 6;
    const int len = lengths[b];
    const float4* p = pts + (size_t)b * N_;
    const int base = slice * SLICE;

    __shared__ float4 s_xy4[SLICE / 2];                   // 32 KB: (xA,yA,xB,yB)
    __shared__ float s_cen[G_][3];                        // CNMS (slice-0, wave-0 only)
    __shared__ unsigned s_bc;                             // stamped winner

    if (t == 0) s_bc = 0u;

    // Stage xy pairs -> LDS; z + running min-dist in registers.
    float zs[PPT], mind[PPT];
#pragma unroll
    for (int i2 = 0; i2 < PPT / 2; i2++) {
        int nA = base + (2 * i2) * FPS_T + t;
        int nB = base + (2 * i2 + 1) * FPS_T + t;
        float4 qA = p[nA];
        float4 qB = p[nB];
        s_xy4[i2 * FPS_T + t] = make_float4(qA.x, qA.y, qB.x, qB.y);
        zs[2 * i2]     = qA.z;
        zs[2 * i2 + 1] = qB.z;
        mind[2 * i2]     = (nA < len) ? INFINITY : -INFINITY;
        mind[2 * i2 + 1] = (nB < len) ? INFINITY : -INFINITY;
    }
    __syncthreads();   // the ONLY barrier (covers s_xy4 staging + s_bc init)

    int n = 0;   // winner index (identical in every wave of batch b)
    for (int k = 0; k < G_; k++) {
        float4 c = p[n];   // wave-uniform broadcast load
        float cx = c.x, cy = c.y, cz = c.z;
        if (slice == 0 && t == 0) {
            centers_out[(b * G_ + k) * 3 + 0] = cx;
            centers_out[(b * G_ + k) * 3 + 1] = cy;
            centers_out[(b * G_ + k) * 3 + 2] = cz;
            s_cen[k][0] = cx; s_cen[k][1] = cy; s_cen[k][2] = cz;
        }
        if (k == G_ - 1) break;   // last argmax is discarded by the reference

        // Local update + argmax (ascending n order => strict > keeps smallest n).
        float bv = -INFINITY;
        int bn = 0x7fffffff;
#pragma unroll
        for (int i2 = 0; i2 < PPT / 2; i2++) {
            float4 xy = s_xy4[i2 * FPS_T + t];            // ds_read_b128, 2 points
            float dA = dist2(xy.x, xy.y, zs[2 * i2],     cx, cy, cz);
            float dB = dist2(xy.z, xy.w, zs[2 * i2 + 1], cx, cy, cz);
            float mA = fminf(mind[2 * i2], dA);
            float mB = fminf(mind[2 * i2 + 1], dB);
            mind[2 * i2] = mA;
            mind[2 * i2 + 1] = mB;
            if (mA > bv) { bv = mA; bn = base + (2 * i2) * FPS_T + t; }
            if (mB > bv) { bv = mB; bn = base + (2 * i2 + 1) * FPS_T + t; }
        }
        // Monotone u32 key of bv (any non-NaN float -> nonzero code).
        unsigned u = __float_as_uint(bv);
        u = (u & 0x80000000u) ? ~u : (u | 0x80000000u);

        // Wave argmax (VALU pipe): max value, then min index among ties.
        unsigned wmax = wave_umax_bcast(u);
        unsigned ik = (u == wmax) ? (unsigned)bn : 0xffffffffu;
        unsigned wbn = wave_umin_bcast(ik);
        unsigned long long kk =
            ((unsigned long long)wmax << 32) | (unsigned)(~wbn);

        // Every wave stores its partial to the fresh per-step slot array.
        unsigned long long* slot = slots + ((size_t)(b * G_ + k)) * NSLOT;
        if (lane == 0)
            __hip_atomic_store(&slot[slice * FPS_W + wv], kk, __ATOMIC_RELAXED,
                               __HIP_MEMORY_SCOPE_AGENT);

        unsigned nn;
        if (wv == 0) {
            // Sole poller: lane i owns slot i; one dwordx2 load per spin.
            unsigned long long v;
            do {
                v = __hip_atomic_load(&slot[lane], __ATOMIC_RELAXED,
                                      __HIP_MEMORY_SCOPE_AGENT);
            } while (__ballot(v == 0ull) != 0ull);
            unsigned hi = (unsigned)(v >> 32);
            unsigned mh = wave_umax_bcast(hi);
            unsigned lo = (hi == mh) ? (unsigned)(v & 0xffffffffull) : 0u;
            unsigned ml = wave_umax_bcast(lo);   // max ~idx among ties = min idx
            nn = ~ml & 0x3fffu;
            if (lane == 0)
                __hip_atomic_store(&s_bc, ((unsigned)(k + 1) << 14) | nn,
                                   __ATOMIC_RELAXED, __HIP_MEMORY_SCOPE_WORKGROUP);
        } else {
            // Spin on the stamped LDS broadcast (same-address, conflict-free).
            unsigned s;
            do {
                s = __hip_atomic_load(&s_bc, __ATOMIC_RELAXED,
                                      __HIP_MEMORY_SCOPE_WORKGROUP);
            } while ((s >> 14) != (unsigned)(k + 1));
            nn = s & 0x3fffu;
        }
        n = (int)nn;
    }

    // ---- fused CNMS on wave 0 of the slice-0 block ----
    if (slice == 0 && t < 64) {
        const float THR = (float)((2.0 * 0.1 * (1.0 - 0.7)) * (2.0 * 0.1 * (1.0 - 0.7)));
        float ax = s_cen[t][0],      ay = s_cen[t][1],      az = s_cen[t][2];
        float ex = s_cen[t + 64][0], ey = s_cen[t + 64][1], ez = s_cen[t + 64][2];
        bool k0 = false, k1 = false;
        for (int j = 0; j < G_; j++) {
            float jx = s_cen[j][0], jy = s_cen[j][1], jz = s_cen[j][2];
            bool c0 = k0 && (dist2(ax, ay, az, jx, jy, jz) < THR);
            bool c1 = k1 && (dist2(ex, ey, ez, jx, jy, jz) < THR);
            bool conflict = __any(c0 || c1);
            if (j == t)      k0 = !conflict;
            if (j == t + 64) k1 = !conflict;
        }
        keep_out[b * G_ + t]      = k0 ? 1 : 0;
        keep_out[b * G_ + t + 64] = k1 ? 1 : 0;
    }
}

// ---------------------------------------------------------------------------
// Kernel 2: per-(b,g) ball query (first 128 by index) + top-32 by energy +
// gather/normalize. One 512-thread block per group.
// ---------------------------------------------------------------------------
__global__ __launch_bounds__(BQ_T) void group_kernel(
    const float4* __restrict__ pts, const int* __restrict__ lengths,
    const float* __restrict__ centers, const int* __restrict__ keep,
    float* __restrict__ groups_out, int* __restrict__ gl) {
    const int bid = blockIdx.x;          // b*128 + g
    const int b = bid >> 7;
    const int t = threadIdx.x;
    const int lane = t & 63;
    const int wv = t >> 6;

    const float cx = centers[bid * 3 + 0];
    const float cy = centers[bid * 3 + 1];
    const float cz = centers[bid * 3 + 2];
    float4* out4 = (float4*)(groups_out + (size_t)bid * GS_ * 4);

    if (!keep[bid]) {
        if (t < GS_) {
            float4 o;
            o.x = __fdiv_rn(__fsub_rn(0.f, cx), 0.1f);
            o.y = __fdiv_rn(__fsub_rn(0.f, cy), 0.1f);
            o.z = __fdiv_rn(__fsub_rn(0.f, cz), 0.1f);
            o.w = 0.f;
            out4[t] = o;
        }
        return;
    }

    __shared__ int   s_widx[BQ_W][UK_];
    __shared__ float s_wen[BQ_W][UK_];
    __shared__ int   s_wcnt[BQ_W];
    __shared__ int   s_list[UK_];
    __shared__ float s_en[UK_];
    __shared__ int   s_ord[GS_];

    const int len = lengths[b];
    const float R2 = (float)(0.1 * 0.1);
    const float4* p = pts + (size_t)b * N_;

    // Per-wave ordered stream compaction over its contiguous eighth.
    {
        const int base0 = wv * (N_ / BQ_W);
        int cnt = 0;
        for (int it = 0; it < (N_ / BQ_W) / 64; it++) {
            int n = base0 + it * 64 + lane;
            float4 q = p[n];
            float d2 = dist2(q.x, q.y, q.z, cx, cy, cz);
            bool pred = (n < len) && (d2 <= R2);
            unsigned long long m = __ballot(pred);
            int prefix = __popcll(m & ((1ull << lane) - 1ull));
            int slot = cnt + prefix;
            if (pred && slot < UK_) { s_widx[wv][slot] = n; s_wen[wv][slot] = q.w; }
            cnt += __popcll(m);
        }
        if (lane == 0) s_wcnt[wv] = (cnt < UK_) ? cnt : UK_;
    }
    __syncthreads();

    int M = 0;
#pragma unroll
    for (int w = 0; w < BQ_W; w++) M += s_wcnt[w];
    if (M > UK_) M = UK_;

    // Ordered merge into unified first-M list.
    if (t < UK_ && t < M) {
        int j = t, w = 0;
        while (w < BQ_W - 1 && j >= s_wcnt[w]) { j -= s_wcnt[w]; w++; }
        s_list[t] = s_widx[w][j];
        s_en[t]   = s_wen[w][j];
    }
    __syncthreads();

    // top-32 by energy, tie -> smaller list position (matches lax.top_k)
    if (wv == 0) {
        float v0 = (lane < M) ? s_en[lane] : -INFINITY;
        float v1 = (lane + 64 < M) ? s_en[lane + 64] : -INFINITY;
        for (int k = 0; k < GS_; k++) {
            float bv; int bs;
            if (v0 >= v1) { bv = v0; bs = lane; }
            else          { bv = v1; bs = lane + 64; }
#pragma unroll
            for (int off = 32; off; off >>= 1) {
                float ov = __shfl_xor(bv, off);
                int   os = __shfl_xor(bs, off);
                bool tk = (ov > bv) || (ov == bv && os < bs);
                bv = tk ? ov : bv; bs = tk ? os : bs;
            }
            if (lane == 0) s_ord[k] = (bv == -INFINITY) ? -1 : bs;
            if (bs == lane)           v0 = -INFINITY;
            else if (bs == lane + 64) v1 = -INFINITY;
        }
    }
    __syncthreads();

    if (t < GS_) {
        int o0 = s_ord[0];
        int first = (o0 >= 0) ? s_list[o0] : -1;
        int ok = s_ord[t];
        int ti = (ok >= 0) ? s_list[ok] : -1;
        int f = (ti == -1) ? first : ti;
        float px = 0.f, py = 0.f, pz = 0.f, pw = 0.f;
        if (f >= 0) { float4 q = p[f]; px = q.x; py = q.y; pz = q.z; pw = q.w; }
        float4 o;
        o.x = __fdiv_rn(__fsub_rn(px, cx), 0.1f);
        o.y = __fdiv_rn(__fsub_rn(py, cy), 0.1f);
        o.z = __fdiv_rn(__fsub_rn(pz, cz), 0.1f);
        o.w = __fdiv_rn(pw, 0.1f);
        out4[t] = o;
    }
    if (t == 0 && M >= GS_) atomicAdd(&gl[b], 1);
}

// ---------------------------------------------------------------------------
// Kernel 3: embedding mask
// ---------------------------------------------------------------------------
__global__ void mask_kernel(const int* __restrict__ gl, float* __restrict__ mask_out) {
    int t = threadIdx.x;                 // 1024 threads
    int b = t >> 7, g = t & 127;
    mask_out[t] = (g < gl[b]) ? 1.0f : 0.0f;
}

extern "C" void kernel_launch(void* const* d_in, const int* in_sizes, int n_in,
                              void* d_out, int out_size, void* d_ws, size_t ws_size,
                              hipStream_t stream) {
    const float4* pts = (const float4*)d_in[0];
    const int* lengths = (const int*)d_in[1];
    float* out = (float*)d_out;
    float* groups = out;                               // B*G*GS*4 = 131072
    float* centers = out + (size_t)B_ * G_ * GS_ * 4;  // +3072
    float* mask = centers + (size_t)B_ * G_ * 3;       // +1024
    unsigned long long* slots = (unsigned long long*)d_ws;  // B*G*NSLOT u64 = 512 KB
    int* keep = (int*)(slots + (size_t)B_ * G_ * NSLOT);    // B*G ints
    int* gl = keep + B_ * G_;                          // B ints

    hipLaunchKernelGGL(init_kernel, dim3((B_ * G_ * NSLOT) / 1024), dim3(1024),
                       0, stream, slots, gl);
    hipLaunchKernelGGL(fps_cnms_kernel, dim3(B_ * FPS_BLK), dim3(FPS_T), 0, stream,
                       pts, lengths, centers, keep, slots);
    hipLaunchKernelGGL(group_kernel, dim3(B_ * G_), dim3(BQ_T), 0, stream,
                       pts, lengths, centers, keep, groups, gl);
    hipLaunchKernelGGL(mask_kernel, dim3(1), dim3(B_ * G_), 0, stream, gl, mask);
}

// Round 14
// 306.736 us; speedup vs baseline: 2.7508x; 1.2626x over previous
//
#include <hip/hip_runtime.h>
#include <math.h>

#define B_ 8
#define N_ 16384
#define G_ 128      // NUM_GROUPS
#define GS_ 32      // GROUP_SIZE
#define UK_ 128     // UPSCALE_K
#define FPS_T 1024
#define FPS_W 16    // waves per FPS block
#define FPS_BLK 4   // blocks (CUs) per batch
#define SLICE (N_ / FPS_BLK)     // 4096 points per block
#define PPT (SLICE / FPS_T)      // 4 points per thread
#define BQ_T 512
#define BQ_W 8      // waves per group block

// Exact-rounding distance^2, matching numpy: ((dx*dx + dy*dy) + dz*dz), no FMA.
__device__ __forceinline__ float dist2(float x, float y, float z,
                                       float cx, float cy, float cz) {
    float dx = __fsub_rn(x, cx);
    float dy = __fsub_rn(y, cy);
    float dz = __fsub_rn(z, cz);
    return __fadd_rn(__fadd_rn(__fmul_rn(dx, dx), __fmul_rn(dy, dy)),
                     __fmul_rn(dz, dz));
}

// Wave64 max-reduce on the VALU pipe via DPP; identity 0; result uniform.
__device__ __forceinline__ unsigned wave_umax_bcast(unsigned v) {
    unsigned t;
    t = (unsigned)__builtin_amdgcn_update_dpp(0, (int)v, 0x111, 0xf, 0xf, false); v = v > t ? v : t;
    t = (unsigned)__builtin_amdgcn_update_dpp(0, (int)v, 0x112, 0xf, 0xf, false); v = v > t ? v : t;
    t = (unsigned)__builtin_amdgcn_update_dpp(0, (int)v, 0x114, 0xf, 0xf, false); v = v > t ? v : t;
    t = (unsigned)__builtin_amdgcn_update_dpp(0, (int)v, 0x118, 0xf, 0xf, false); v = v > t ? v : t;
    t = (unsigned)__builtin_amdgcn_update_dpp(0, (int)v, 0x142, 0xa, 0xf, false); v = v > t ? v : t;
    t = (unsigned)__builtin_amdgcn_update_dpp(0, (int)v, 0x143, 0xc, 0xf, false); v = v > t ? v : t;
    return (unsigned)__builtin_amdgcn_readlane((int)v, 63);
}

// ---------------------------------------------------------------------------
// Kernel 1: FPS, 4 blocks per batch, ZERO barriers in the K-loop.
//
// Sync laws learned (r9-r13): few atomic writers (4/batch), few polling
// waves (4/batch), and HOT slot addresses (r13's fresh-line-per-step
// streamed 2MB of 32B write-throughs to HBM). Design: every exchanged
// word carries a stamp in lo32 ((k+1)<<14 | (~bn&0x3fff)); readers
// stamp-spin, so no barriers/init are needed. Parity-2 address
// alternation (reuse every 2 steps) makes the overwrite window ~2 full
// steps >> poll RTT (no deadlock/stale reads). Global slots: 64 u64
// TOTAL (512B, LLC-hot). Merges: two-phase DPP (max hi32 = dist key,
// then max lo32 = ~idx among hi-ties = min index) - bit-identical
// winner, no dependent u64 shfl chains.
// ---------------------------------------------------------------------------
__global__ __launch_bounds__(FPS_T, 4) void fps_cnms_kernel(
    const float4* __restrict__ pts, const int* __restrict__ lengths,
    float* __restrict__ centers_out, int* __restrict__ keep_out,
    unsigned long long* __restrict__ gslots, int* __restrict__ gl) {
    const int b = blockIdx.x & 7;        // batch
    const int slice = blockIdx.x >> 3;   // 0..3
    const int t = threadIdx.x;
    const int lane = t & 63;
    const int wv = t >> 6;
    const int len = lengths[b];
    const float4* p = pts + (size_t)b * N_;
    const int base = slice * SLICE;

    __shared__ float4 s_xy4[SLICE / 2];                   // 32 KB: (xA,yA,xB,yB)
    __shared__ unsigned long long s_part[2][FPS_W];       // stamped wave partials
    __shared__ unsigned s_bc[2];                          // stamped winner relay
    __shared__ float s_cen[G_][3];                        // CNMS (slice-0, wave-0)

    if (slice == 0 && t == 0) gl[b] = 0;                  // replaces init_kernel
    if (t < 2 * FPS_W) ((unsigned long long*)s_part)[t] = 0ull;
    if (t < 2) s_bc[t] = 0u;

    // Stage xy pairs -> LDS; z + running min-dist in registers.
    float zs[PPT], mind[PPT];
#pragma unroll
    for (int i2 = 0; i2 < PPT / 2; i2++) {
        int nA = base + (2 * i2) * FPS_T + t;
        int nB = base + (2 * i2 + 1) * FPS_T + t;
        float4 qA = p[nA];
        float4 qB = p[nB];
        s_xy4[i2 * FPS_T + t] = make_float4(qA.x, qA.y, qB.x, qB.y);
        zs[2 * i2]     = qA.z;
        zs[2 * i2 + 1] = qB.z;
        mind[2 * i2]     = (nA < len) ? INFINITY : -INFINITY;
        mind[2 * i2 + 1] = (nB < len) ? INFINITY : -INFINITY;
    }
    __syncthreads();   // the ONLY barrier (staging + LDS stamp init)

    int n = 0;   // winner index (identical in every wave of batch b)
    for (int k = 0; k < G_; k++) {
        float4 c = p[n];   // wave-uniform broadcast load
        float cx = c.x, cy = c.y, cz = c.z;
        if (slice == 0 && t == 0) {
            centers_out[(b * G_ + k) * 3 + 0] = cx;
            centers_out[(b * G_ + k) * 3 + 1] = cy;
            centers_out[(b * G_ + k) * 3 + 2] = cz;
            s_cen[k][0] = cx; s_cen[k][1] = cy; s_cen[k][2] = cz;
        }
        if (k == G_ - 1) break;   // last argmax is discarded by the reference

        // Local update + argmax (ascending n order => strict > keeps smallest n).
        float bv = -INFINITY;
        int bn = 0x7fffffff;
#pragma unroll
        for (int i2 = 0; i2 < PPT / 2; i2++) {
            float4 xy = s_xy4[i2 * FPS_T + t];            // ds_read_b128, 2 points
            float dA = dist2(xy.x, xy.y, zs[2 * i2],     cx, cy, cz);
            float dB = dist2(xy.z, xy.w, zs[2 * i2 + 1], cx, cy, cz);
            float mA = fminf(mind[2 * i2], dA);
            float mB = fminf(mind[2 * i2 + 1], dB);
            mind[2 * i2] = mA;
            mind[2 * i2 + 1] = mB;
            if (mA > bv) { bv = mA; bn = base + (2 * i2) * FPS_T + t; }
            if (mB > bv) { bv = mB; bn = base + (2 * i2 + 1) * FPS_T + t; }
        }
        // Monotone u32 key of bv (nonzero for any non-NaN float).
        unsigned u = __float_as_uint(bv);
        u = (u & 0x80000000u) ? ~u : (u | 0x80000000u);

        const unsigned stamp = (unsigned)(k + 1) << 14;

        // Wave argmax: max key, then max (~bn&0x3fff) among ties = min index.
        unsigned wmax = wave_umax_bcast(u);
        unsigned ik = (u == wmax) ? ((unsigned)~bn & 0x3fffu) : 0u;
        unsigned wlo = wave_umax_bcast(ik);
        unsigned long long kk =
            ((unsigned long long)wmax << 32) | (stamp | wlo);

        // Stamped wave partial -> LDS (no barrier).
        if (lane == 0)
            __hip_atomic_store(&s_part[k & 1][wv], kk, __ATOMIC_RELAXED,
                               __HIP_MEMORY_SCOPE_WORKGROUP);

        unsigned nn;
        if (wv == 0) {
            // Gather 16 stamped partials (lane&15; duplicates harmless).
            unsigned long long v;
            do {
                v = __hip_atomic_load(&s_part[k & 1][lane & 15], __ATOMIC_RELAXED,
                                      __HIP_MEMORY_SCOPE_WORKGROUP);
            } while (__ballot(((unsigned)v >> 14) != (unsigned)(k + 1)) != 0ull);
            unsigned hi = (unsigned)(v >> 32);
            unsigned mh = wave_umax_bcast(hi);
            unsigned lo = (hi == mh) ? (unsigned)v : 0u;
            unsigned ml = wave_umax_bcast(lo);
            unsigned long long bkk = ((unsigned long long)mh << 32) | ml;

            // Cross-block: 4 hot slots (one 32B line), parity-2 reuse.
            unsigned long long* gs = gslots + (size_t)(k & 1) * 32 + b * FPS_BLK;
            if (lane == 0)
                __hip_atomic_store(&gs[slice], bkk, __ATOMIC_RELAXED,
                                   __HIP_MEMORY_SCOPE_AGENT);
            unsigned long long w;
            do {
                w = __hip_atomic_load(&gs[lane & 3], __ATOMIC_RELAXED,
                                      __HIP_MEMORY_SCOPE_AGENT);
            } while (__ballot(((unsigned)w >> 14) != (unsigned)(k + 1)) != 0ull);
            unsigned hi2 = (unsigned)(w >> 32);
            unsigned mh2 = wave_umax_bcast(hi2);
            unsigned lo2 = (hi2 == mh2) ? (unsigned)w : 0u;
            unsigned ml2 = wave_umax_bcast(lo2);
            nn = (unsigned)(~ml2) & 0x3fffu;
            if (lane == 0)
                __hip_atomic_store(&s_bc[k & 1], stamp | nn, __ATOMIC_RELAXED,
                                   __HIP_MEMORY_SCOPE_WORKGROUP);
        } else {
            // Stamped LDS relay (same-address broadcast, conflict-free).
            unsigned s;
            do {
                s = __hip_atomic_load(&s_bc[k & 1], __ATOMIC_RELAXED,
                                      __HIP_MEMORY_SCOPE_WORKGROUP);
            } while ((s >> 14) != (unsigned)(k + 1));
            nn = s & 0x3fffu;
        }
        n = (int)nn;
    }

    // ---- fused CNMS on wave 0 of the slice-0 block ----
    if (slice == 0 && t < 64) {
        const float THR = (float)((2.0 * 0.1 * (1.0 - 0.7)) * (2.0 * 0.1 * (1.0 - 0.7)));
        float ax = s_cen[t][0],      ay = s_cen[t][1],      az = s_cen[t][2];
        float ex = s_cen[t + 64][0], ey = s_cen[t + 64][1], ez = s_cen[t + 64][2];
        bool k0 = false, k1 = false;
        for (int j = 0; j < G_; j++) {
            float jx = s_cen[j][0], jy = s_cen[j][1], jz = s_cen[j][2];
            bool c0 = k0 && (dist2(ax, ay, az, jx, jy, jz) < THR);
            bool c1 = k1 && (dist2(ex, ey, ez, jx, jy, jz) < THR);
            bool conflict = __any(c0 || c1);
            if (j == t)      k0 = !conflict;
            if (j == t + 64) k1 = !conflict;
        }
        keep_out[b * G_ + t]      = k0 ? 1 : 0;
        keep_out[b * G_ + t + 64] = k1 ? 1 : 0;
    }
}

// ---------------------------------------------------------------------------
// Kernel 2: per-(b,g) ball query (first 128 by index) + top-32 by energy +
// gather/normalize. One 512-thread block per group.
// ---------------------------------------------------------------------------
__global__ __launch_bounds__(BQ_T) void group_kernel(
    const float4* __restrict__ pts, const int* __restrict__ lengths,
    const float* __restrict__ centers, const int* __restrict__ keep,
    float* __restrict__ groups_out, int* __restrict__ gl) {
    const int bid = blockIdx.x;          // b*128 + g
    const int b = bid >> 7;
    const int t = threadIdx.x;
    const int lane = t & 63;
    const int wv = t >> 6;

    const float cx = centers[bid * 3 + 0];
    const float cy = centers[bid * 3 + 1];
    const float cz = centers[bid * 3 + 2];
    float4* out4 = (float4*)(groups_out + (size_t)bid * GS_ * 4);

    if (!keep[bid]) {
        if (t < GS_) {
            float4 o;
            o.x = __fdiv_rn(__fsub_rn(0.f, cx), 0.1f);
            o.y = __fdiv_rn(__fsub_rn(0.f, cy), 0.1f);
            o.z = __fdiv_rn(__fsub_rn(0.f, cz), 0.1f);
            o.w = 0.f;
            out4[t] = o;
        }
        return;
    }

    __shared__ int   s_widx[BQ_W][UK_];
    __shared__ float s_wen[BQ_W][UK_];
    __shared__ int   s_wcnt[BQ_W];
    __shared__ int   s_list[UK_];
    __shared__ float s_en[UK_];
    __shared__ int   s_ord[GS_];

    const int len = lengths[b];
    const float R2 = (float)(0.1 * 0.1);
    const float4* p = pts + (size_t)b * N_;

    // Per-wave ordered stream compaction over its contiguous eighth.
    {
        const int base0 = wv * (N_ / BQ_W);
        int cnt = 0;
        for (int it = 0; it < (N_ / BQ_W) / 64; it++) {
            int n = base0 + it * 64 + lane;
            float4 q = p[n];
            float d2 = dist2(q.x, q.y, q.z, cx, cy, cz);
            bool pred = (n < len) && (d2 <= R2);
            unsigned long long m = __ballot(pred);
            int prefix = __popcll(m & ((1ull << lane) - 1ull));
            int slot = cnt + prefix;
            if (pred && slot < UK_) { s_widx[wv][slot] = n; s_wen[wv][slot] = q.w; }
            cnt += __popcll(m);
        }
        if (lane == 0) s_wcnt[wv] = (cnt < UK_) ? cnt : UK_;
    }
    __syncthreads();

    int M = 0;
#pragma unroll
    for (int w = 0; w < BQ_W; w++) M += s_wcnt[w];
    if (M > UK_) M = UK_;

    // Ordered merge into unified first-M list.
    if (t < UK_ && t < M) {
        int j = t, w = 0;
        while (w < BQ_W - 1 && j >= s_wcnt[w]) { j -= s_wcnt[w]; w++; }
        s_list[t] = s_widx[w][j];
        s_en[t]   = s_wen[w][j];
    }
    __syncthreads();

    // top-32 by energy, tie -> smaller list position (matches lax.top_k)
    if (wv == 0) {
        float v0 = (lane < M) ? s_en[lane] : -INFINITY;
        float v1 = (lane + 64 < M) ? s_en[lane + 64] : -INFINITY;
        for (int k = 0; k < GS_; k++) {
            float bv; int bs;
            if (v0 >= v1) { bv = v0; bs = lane; }
            else          { bv = v1; bs = lane + 64; }
#pragma unroll
            for (int off = 32; off; off >>= 1) {
                float ov = __shfl_xor(bv, off);
                int   os = __shfl_xor(bs, off);
                bool tk = (ov > bv) || (ov == bv && os < bs);
                bv = tk ? ov : bv; bs = tk ? os : bs;
            }
            if (lane == 0) s_ord[k] = (bv == -INFINITY) ? -1 : bs;
            if (bs == lane)           v0 = -INFINITY;
            else if (bs == lane + 64) v1 = -INFINITY;
        }
    }
    __syncthreads();

    if (t < GS_) {
        int o0 = s_ord[0];
        int first = (o0 >= 0) ? s_list[o0] : -1;
        int ok = s_ord[t];
        int ti = (ok >= 0) ? s_list[ok] : -1;
        int f = (ti == -1) ? first : ti;
        float px = 0.f, py = 0.f, pz = 0.f, pw = 0.f;
        if (f >= 0) { float4 q = p[f]; px = q.x; py = q.y; pz = q.z; pw = q.w; }
        float4 o;
        o.x = __fdiv_rn(__fsub_rn(px, cx), 0.1f);
        o.y = __fdiv_rn(__fsub_rn(py, cy), 0.1f);
        o.z = __fdiv_rn(__fsub_rn(pz, cz), 0.1f);
        o.w = __fdiv_rn(pw, 0.1f);
        out4[t] = o;
    }
    if (t == 0 && M >= GS_) atomicAdd(&gl[b], 1);
}

// ---------------------------------------------------------------------------
// Kernel 3: embedding mask
// ---------------------------------------------------------------------------
__global__ void mask_kernel(const int* __restrict__ gl, float* __restrict__ mask_out) {
    int t = threadIdx.x;                 // 1024 threads
    int b = t >> 7, g = t & 127;
    mask_out[t] = (g < gl[b]) ? 1.0f : 0.0f;
}

extern "C" void kernel_launch(void* const* d_in, const int* in_sizes, int n_in,
                              void* d_out, int out_size, void* d_ws, size_t ws_size,
                              hipStream_t stream) {
    const float4* pts = (const float4*)d_in[0];
    const int* lengths = (const int*)d_in[1];
    float* out = (float*)d_out;
    float* groups = out;                               // B*G*GS*4 = 131072
    float* centers = out + (size_t)B_ * G_ * GS_ * 4;  // +3072
    float* mask = centers + (size_t)B_ * G_ * 3;       // +1024
    unsigned long long* gslots = (unsigned long long*)d_ws;  // 64 u64 (2 parities x 32)
    int* keep = (int*)(gslots + 64);                   // B*G ints
    int* gl = keep + B_ * G_;                          // B ints

    hipLaunchKernelGGL(fps_cnms_kernel, dim3(B_ * FPS_BLK), dim3(FPS_T), 0, stream,
                       pts, lengths, centers, keep, gslots, gl);
    hipLaunchKernelGGL(group_kernel, dim3(B_ * G_), dim3(BQ_T), 0, stream,
                       pts, lengths, centers, keep, groups, gl);
    hipLaunchKernelGGL(mask_kernel, dim3(1), dim3(B_ * G_), 0, stream, gl, mask);
}